// Round 6
// baseline (276.677 us; speedup 1.0000x reference)
//
#include <hip/hip_runtime.h>

#define N_NODES 50000
#define N_EDGES 400000
#define DIM 160
#define NB 64
#define CUTOFF 5.0f
#define LN_EPS 1e-5f
#define PI_F 3.14159265358979323846f

// Workspace (ints): [0..15] ew(float)+pad | deg[N] | offs[50004] | cursor[N] | esrc[E]
#define WS_DEG    16
#define WS_OFFS   (WS_DEG + N_NODES)        // 16B aligned
#define WS_CURSOR (WS_OFFS + 50004)         // 16B aligned
#define WS_ESRC   (WS_CURSOR + N_NODES)

// ---------------------------------------------------------------------------
// K1: thread-per-edge. dst histogram (int atomics) + edge_w sigmoid sum.
// ---------------------------------------------------------------------------
__global__ __launch_bounds__(256) void hist_ew(
    const int* __restrict__ ei, const float* __restrict__ pos,
    const float* __restrict__ centers, const float* __restrict__ widths,
    const float* __restrict__ proj_w, const float* __restrict__ proj_b,
    int* __restrict__ deg, float* __restrict__ ew_accum)
{
    __shared__ float sc_c[NB], sc_iw[NB], sc_p[NB];
    if (threadIdx.x < NB) {
        sc_c[threadIdx.x]  = centers[threadIdx.x];
        sc_iw[threadIdx.x] = 1.0f / widths[threadIdx.x];
        sc_p[threadIdx.x]  = proj_w[threadIdx.x];
    }
    __syncthreads();

    const float bias = proj_b[0];
    const int e = blockIdx.x * blockDim.x + threadIdx.x;
    float sig = 0.0f;
    if (e < N_EDGES) {
        const int s = ei[e];
        const int d = ei[N_EDGES + e];
        atomicAdd(&deg[d], 1);

        const float dx = pos[3 * s]     - pos[3 * d];
        const float dy = pos[3 * s + 1] - pos[3 * d + 1];
        const float dz = pos[3 * s + 2] - pos[3 * d + 2];
        const float dist = sqrtf(dx * dx + dy * dy + dz * dz);

        float z = 0.0f;
        #pragma unroll 8
        for (int b = 0; b < NB; ++b) {
            const float t = (dist - sc_c[b]) * sc_iw[b];
            z += __expf(-0.5f * t * t) * sc_p[b];
        }
        const float cut = (dist <= CUTOFF)
                        ? 0.5f * (__cosf(PI_F * dist * (1.0f / CUTOFF)) + 1.0f)
                        : 0.0f;
        sig = 1.0f / (1.0f + __expf(-(z * cut + bias)));
    }

    #pragma unroll
    for (int off = 32; off > 0; off >>= 1) sig += __shfl_xor(sig, off);
    __shared__ float red[4];
    if ((threadIdx.x & 63) == 0) red[threadIdx.x >> 6] = sig;
    __syncthreads();
    if (threadIdx.x == 0)
        atomicAdd(ew_accum, red[0] + red[1] + red[2] + red[3]);
}

// ---------------------------------------------------------------------------
// K2: single-block exclusive scan, int4-vectorized.
// ---------------------------------------------------------------------------
__global__ __launch_bounds__(1024) void scan_deg(
    const int* __restrict__ deg, int* __restrict__ offs, int* __restrict__ cursor)
{
    __shared__ int wsum[16];
    const int tid = threadIdx.x, lane = tid & 63, w = tid >> 6;
    const int4* d4 = (const int4*)deg;
    int4* o4 = (int4*)offs;
    int4* c4 = (int4*)cursor;
    int carry = 0;
    const int NV = N_NODES / 4;
    for (int base = 0; base < NV; base += 1024) {
        const int i = base + tid;
        int4 v = make_int4(0, 0, 0, 0);
        if (i < NV) v = d4[i];
        const int loc = v.x + v.y + v.z + v.w;
        int sc = loc;
        #pragma unroll
        for (int off = 1; off < 64; off <<= 1) {
            const int t = __shfl_up(sc, off);
            if (lane >= off) sc += t;
        }
        if (lane == 63) wsum[w] = sc;
        __syncthreads();
        if (w == 0) {
            int s = (lane < 16) ? wsum[lane] : 0;
            #pragma unroll
            for (int off = 1; off < 16; off <<= 1) {
                const int t = __shfl_up(s, off);
                if (lane >= off) s += t;
            }
            if (lane < 16) wsum[lane] = s;
        }
        __syncthreads();
        const int wpre = (w > 0) ? wsum[w - 1] : 0;
        const int excl = carry + wpre + sc - loc;
        if (i < NV) {
            int4 o;
            o.x = excl;
            o.y = o.x + v.x;
            o.z = o.y + v.y;
            o.w = o.z + v.z;
            o4[i] = o;
            c4[i] = o;
        }
        carry += wsum[15];
        __syncthreads();
    }
    if (tid == 0) offs[N_NODES] = carry;
}

// ---------------------------------------------------------------------------
// K3: thread-per-edge fill of CSR edge-source list.
// ---------------------------------------------------------------------------
__global__ __launch_bounds__(256) void fill_csr(
    const int* __restrict__ ei, int* __restrict__ cursor, int* __restrict__ esrc)
{
    const int e = blockIdx.x * blockDim.x + threadIdx.x;
    if (e >= N_EDGES) return;
    const int s = ei[e];
    const int d = ei[N_EDGES + e];
    const int p = atomicAdd(&cursor[d], 1);
    esrc[p] = s;
}

// ---------------------------------------------------------------------------
// K4: wave-per-node gather (unchanged from round 5, 41 us measured).
// ---------------------------------------------------------------------------
__global__ __launch_bounds__(256) void gather_pass(
    const float* __restrict__ x, const int* __restrict__ offs,
    const int* __restrict__ esrc, float* __restrict__ agg)
{
    const int lane = threadIdx.x & 63;
    const int n    = (blockIdx.x * blockDim.x + threadIdx.x) >> 6;
    if (n >= N_NODES) return;

    const int beg = offs[n];
    const int end = offs[n + 1];

    float4 acc = make_float4(0.f, 0.f, 0.f, 0.f);
    for (int k0 = beg; k0 < end; k0 += 64) {
        const int cnt = min(64, end - k0);
        const int sv  = (lane < cnt) ? esrc[k0 + lane] : 0;
        int j = 0;
        for (; j + 4 <= cnt; j += 4) {
            const int s0 = __shfl(sv, j);
            const int s1 = __shfl(sv, j + 1);
            const int s2 = __shfl(sv, j + 2);
            const int s3 = __shfl(sv, j + 3);
            if (lane < 40) {
                const float4 v0 = ((const float4*)(x + (long)s0 * DIM))[lane];
                const float4 v1 = ((const float4*)(x + (long)s1 * DIM))[lane];
                const float4 v2 = ((const float4*)(x + (long)s2 * DIM))[lane];
                const float4 v3 = ((const float4*)(x + (long)s3 * DIM))[lane];
                acc.x += (v0.x + v1.x) + (v2.x + v3.x);
                acc.y += (v0.y + v1.y) + (v2.y + v3.y);
                acc.z += (v0.z + v1.z) + (v2.z + v3.z);
                acc.w += (v0.w + v1.w) + (v2.w + v3.w);
            }
        }
        for (; j < cnt; ++j) {
            const int s0 = __shfl(sv, j);
            if (lane < 40) {
                const float4 v0 = ((const float4*)(x + (long)s0 * DIM))[lane];
                acc.x += v0.x; acc.y += v0.y; acc.z += v0.z; acc.w += v0.w;
            }
        }
    }
    if (lane < 40)
        ((float4*)(agg + (long)n * DIM))[lane] = acc;
}

// ---------------------------------------------------------------------------
// K5: FUSED node transform, 4 threads per node per channel.
//  Blocks [0, NA): scalar channel. thread -> (node, chunk of 16 outputs).
//    acc[16] in VGPRs; LN stats via 2 shfl_xor rounds over the 4-lane group.
//  Blocks [NA, NA+NB): vector channel. thread -> (node, 8 c-channels = 24 out).
//  Both phases co-resident (one launch, ~6 waves/SIMD) to hide VMEM latency.
// ---------------------------------------------------------------------------
#define NA_BLOCKS ((N_NODES * 4 + 255) / 256)   // 782
#define NB_BLOCKS ((N_NODES * 4 + 255) / 256)   // 782

__global__ __launch_bounds__(256) void node_fused(
    float* __restrict__ agg,
    const float* __restrict__ W0, const float* __restrict__ W1,
    const float* __restrict__ ln_gamma, const float* __restrict__ ln_beta,
    const float* __restrict__ ew_accum)
{
    const float ew = ew_accum[0] * (1.0f / 400000.0f);

    if (blockIdx.x < NA_BLOCKS) {
        // ---------------- scalar channel ----------------
        const int gtid  = blockIdx.x * 256 + threadIdx.x;
        const int node  = gtid >> 2;
        const int chunk = gtid & 3;            // outputs j in [16*chunk, 16*chunk+16)
        const bool valid = node < N_NODES;
        const int nc    = valid ? node : (N_NODES - 1);
        float* row = agg + (long)nc * DIM;
        const float4* row4 = (const float4*)row;
        const float s_m0 = ew * 0.125f;        // / sqrt(64)

        float acc[16];
        #pragma unroll
        for (int j = 0; j < 16; ++j) acc[j] = 0.0f;

        #pragma unroll 4
        for (int q = 0; q < 16; ++q) {         // k = 4q + r
            const float4 a4 = row4[q];
            #pragma unroll
            for (int r = 0; r < 4; ++r) {
                const float a = (r == 0) ? a4.x : (r == 1) ? a4.y : (r == 2) ? a4.z : a4.w;
                const float4* w4 = (const float4*)(W0 + (4 * q + r) * 64 + chunk * 16);
                #pragma unroll
                for (int p = 0; p < 4; ++p) {
                    const float4 wv = w4[p];
                    acc[4 * p]     = fmaf(a, wv.x, acc[4 * p]);
                    acc[4 * p + 1] = fmaf(a, wv.y, acc[4 * p + 1]);
                    acc[4 * p + 2] = fmaf(a, wv.z, acc[4 * p + 2]);
                    acc[4 * p + 3] = fmaf(a, wv.w, acc[4 * p + 3]);
                }
            }
        }

        // partial LN stats over this thread's 16, reduce across the 4-lane group
        float sum = 0.0f, sumsq = 0.0f;
        #pragma unroll
        for (int j = 0; j < 16; ++j) {
            acc[j] *= s_m0;
            sum += acc[j];
            sumsq = fmaf(acc[j], acc[j], sumsq);
        }
        sum   += __shfl_xor(sum, 1);   sumsq += __shfl_xor(sumsq, 1);
        sum   += __shfl_xor(sum, 2);   sumsq += __shfl_xor(sumsq, 2);
        const float mu   = sum * (1.0f / 64.0f);
        const float var  = sumsq * (1.0f / 64.0f) - mu * mu;
        const float rstd = rsqrtf(var + LN_EPS);

        if (valid) {
            const float4* g4 = (const float4*)(ln_gamma + chunk * 16);
            const float4* b4 = (const float4*)(ln_beta  + chunk * 16);
            float4* ro4 = (float4*)(row + chunk * 16);
            #pragma unroll
            for (int p = 0; p < 4; ++p) {
                const float4 g = g4[p];
                const float4 b = b4[p];
                const float t0 = (acc[4 * p]     - mu) * rstd * g.x + b.x;
                const float t1 = (acc[4 * p + 1] - mu) * rstd * g.y + b.y;
                const float t2 = (acc[4 * p + 2] - mu) * rstd * g.z + b.z;
                const float t3 = (acc[4 * p + 3] - mu) * rstd * g.w + b.w;
                float4 o;
                o.x = t0 / (1.0f + __expf(-t0));
                o.y = t1 / (1.0f + __expf(-t1));
                o.z = t2 / (1.0f + __expf(-t2));
                o.w = t3 / (1.0f + __expf(-t3));
                ro4[p] = o;
            }
        }
    } else {
        // ---------------- vector channel ----------------
        const int gtid  = (blockIdx.x - NA_BLOCKS) * 256 + threadIdx.x;
        const int node  = gtid >> 2;
        const int c8    = gtid & 3;            // c in [8*c8, 8*c8+8) -> 24 outputs
        const bool valid = node < N_NODES;
        const int nc    = valid ? node : (N_NODES - 1);
        float* rowB = agg + (long)nc * DIM + 64;
        const float4* r4 = (const float4*)rowB;
        const float s_m1 = ew * 0.17677669529663687f;   // / sqrt(32)

        float o[24];
        #pragma unroll
        for (int m = 0; m < 24; ++m) o[m] = 0.0f;

        #pragma unroll 2
        for (int t = 0; t < 8; ++t) {          // cp = 4t + r
            const float4 v0 = r4[3 * t];
            const float4 v1 = r4[3 * t + 1];
            const float4 v2 = r4[3 * t + 2];
            const float a[12] = { v0.x, v0.y, v0.z, v0.w,
                                  v1.x, v1.y, v1.z, v1.w,
                                  v2.x, v2.y, v2.z, v2.w };
            #pragma unroll
            for (int r = 0; r < 4; ++r) {
                const int cp = 4 * t + r;
                const float a0 = a[3 * r];
                const float a1 = a[3 * r + 1];
                const float a2 = a[3 * r + 2];
                const float4* w4 = (const float4*)(W1 + cp * 32 + c8 * 8);
                const float4 wA = w4[0];
                const float4 wB = w4[1];
                const float wc[8] = { wA.x, wA.y, wA.z, wA.w, wB.x, wB.y, wB.z, wB.w };
                #pragma unroll
                for (int cc = 0; cc < 8; ++cc) {
                    o[3 * cc]     = fmaf(wc[cc], a0, o[3 * cc]);
                    o[3 * cc + 1] = fmaf(wc[cc], a1, o[3 * cc + 1]);
                    o[3 * cc + 2] = fmaf(wc[cc], a2, o[3 * cc + 2]);
                }
            }
        }

        if (valid) {
            float4* ro4 = (float4*)(rowB + 24 * c8);   // 24*c8 is 16B-aligned
            #pragma unroll
            for (int q = 0; q < 6; ++q) {
                float4 ov;
                ov.x = o[4 * q]     * s_m1;
                ov.y = o[4 * q + 1] * s_m1;
                ov.z = o[4 * q + 2] * s_m1;
                ov.w = o[4 * q + 3] * s_m1;
                ro4[q] = ov;
            }
        }
    }
}

extern "C" void kernel_launch(void* const* d_in, const int* in_sizes, int n_in,
                              void* d_out, int out_size, void* d_ws, size_t ws_size,
                              hipStream_t stream) {
    const float* x       = (const float*)d_in[0];
    const float* pos     = (const float*)d_in[1];
    const int*   ei      = (const int*)d_in[2];
    const float* W0      = (const float*)d_in[4];
    const float* W1      = (const float*)d_in[5];
    const float* centers = (const float*)d_in[6];
    const float* widths  = (const float*)d_in[7];
    const float* proj_w  = (const float*)d_in[8];
    const float* proj_b  = (const float*)d_in[9];
    const float* gamma   = (const float*)d_in[10];
    const float* beta    = (const float*)d_in[11];

    float* out  = (float*)d_out;
    int*   wsi  = (int*)d_ws;
    float* ew   = (float*)d_ws;
    int*   deg  = wsi + WS_DEG;
    int*   offs = wsi + WS_OFFS;
    int*   curs = wsi + WS_CURSOR;
    int*   esrc = wsi + WS_ESRC;

    hipMemsetAsync(d_ws, 0, (size_t)(WS_DEG + N_NODES) * sizeof(int), stream);

    const int eb = (N_EDGES + 255) / 256;
    hist_ew <<<eb, 256, 0, stream>>>(ei, pos, centers, widths, proj_w, proj_b, deg, ew);
    scan_deg<<<1, 1024, 0, stream>>>(deg, offs, curs);
    fill_csr<<<eb, 256, 0, stream>>>(ei, curs, esrc);

    const int nb = (N_NODES * 64 + 255) / 256;
    gather_pass<<<nb, 256, 0, stream>>>(x, offs, esrc, out);

    node_fused<<<NA_BLOCKS + NB_BLOCKS, 256, 0, stream>>>(out, W0, W1, gamma, beta, ew);
}

// Round 7
// 236.960 us; speedup vs baseline: 1.1676x; 1.1676x over previous
//
#include <hip/hip_runtime.h>

#define N_NODES 50000
#define N_EDGES 400000
#define DIM 160
#define NB 64
#define CUTOFF 5.0f
#define LN_EPS 1e-5f
#define PI_F 3.14159265358979323846f

// Workspace (ints): [0..15] ew(float)+pad | deg[N] | offs[50004] | cursor[N] | esrc[E]
#define WS_DEG    16
#define WS_OFFS   (WS_DEG + N_NODES)        // 16B aligned
#define WS_CURSOR (WS_OFFS + 50004)         // 16B aligned
#define WS_ESRC   (WS_CURSOR + N_NODES)

// ---------------------------------------------------------------------------
// K1: thread-per-edge. dst histogram (int atomics) + edge_w sigmoid sum.
// ---------------------------------------------------------------------------
__global__ __launch_bounds__(256) void hist_ew(
    const int* __restrict__ ei, const float* __restrict__ pos,
    const float* __restrict__ centers, const float* __restrict__ widths,
    const float* __restrict__ proj_w, const float* __restrict__ proj_b,
    int* __restrict__ deg, float* __restrict__ ew_accum)
{
    __shared__ float sc_c[NB], sc_iw[NB], sc_p[NB];
    if (threadIdx.x < NB) {
        sc_c[threadIdx.x]  = centers[threadIdx.x];
        sc_iw[threadIdx.x] = 1.0f / widths[threadIdx.x];
        sc_p[threadIdx.x]  = proj_w[threadIdx.x];
    }
    __syncthreads();

    const float bias = proj_b[0];
    const int e = blockIdx.x * blockDim.x + threadIdx.x;
    float sig = 0.0f;
    if (e < N_EDGES) {
        const int s = ei[e];
        const int d = ei[N_EDGES + e];
        atomicAdd(&deg[d], 1);

        const float dx = pos[3 * s]     - pos[3 * d];
        const float dy = pos[3 * s + 1] - pos[3 * d + 1];
        const float dz = pos[3 * s + 2] - pos[3 * d + 2];
        const float dist = sqrtf(dx * dx + dy * dy + dz * dz);

        float z = 0.0f;
        #pragma unroll 8
        for (int b = 0; b < NB; ++b) {
            const float t = (dist - sc_c[b]) * sc_iw[b];
            z += __expf(-0.5f * t * t) * sc_p[b];
        }
        const float cut = (dist <= CUTOFF)
                        ? 0.5f * (__cosf(PI_F * dist * (1.0f / CUTOFF)) + 1.0f)
                        : 0.0f;
        sig = 1.0f / (1.0f + __expf(-(z * cut + bias)));
    }

    #pragma unroll
    for (int off = 32; off > 0; off >>= 1) sig += __shfl_xor(sig, off);
    __shared__ float red[4];
    if ((threadIdx.x & 63) == 0) red[threadIdx.x >> 6] = sig;
    __syncthreads();
    if (threadIdx.x == 0)
        atomicAdd(ew_accum, red[0] + red[1] + red[2] + red[3]);
}

// ---------------------------------------------------------------------------
// K2: single-block exclusive scan, int4-vectorized.
// ---------------------------------------------------------------------------
__global__ __launch_bounds__(1024) void scan_deg(
    const int* __restrict__ deg, int* __restrict__ offs, int* __restrict__ cursor)
{
    __shared__ int wsum[16];
    const int tid = threadIdx.x, lane = tid & 63, w = tid >> 6;
    const int4* d4 = (const int4*)deg;
    int4* o4 = (int4*)offs;
    int4* c4 = (int4*)cursor;
    int carry = 0;
    const int NV = N_NODES / 4;
    for (int base = 0; base < NV; base += 1024) {
        const int i = base + tid;
        int4 v = make_int4(0, 0, 0, 0);
        if (i < NV) v = d4[i];
        const int loc = v.x + v.y + v.z + v.w;
        int sc = loc;
        #pragma unroll
        for (int off = 1; off < 64; off <<= 1) {
            const int t = __shfl_up(sc, off);
            if (lane >= off) sc += t;
        }
        if (lane == 63) wsum[w] = sc;
        __syncthreads();
        if (w == 0) {
            int s = (lane < 16) ? wsum[lane] : 0;
            #pragma unroll
            for (int off = 1; off < 16; off <<= 1) {
                const int t = __shfl_up(s, off);
                if (lane >= off) s += t;
            }
            if (lane < 16) wsum[lane] = s;
        }
        __syncthreads();
        const int wpre = (w > 0) ? wsum[w - 1] : 0;
        const int excl = carry + wpre + sc - loc;
        if (i < NV) {
            int4 o;
            o.x = excl;
            o.y = o.x + v.x;
            o.z = o.y + v.y;
            o.w = o.z + v.z;
            o4[i] = o;
            c4[i] = o;
        }
        carry += wsum[15];
        __syncthreads();
    }
    if (tid == 0) offs[N_NODES] = carry;
}

// ---------------------------------------------------------------------------
// K3: thread-per-edge fill of CSR edge-source list.
// ---------------------------------------------------------------------------
__global__ __launch_bounds__(256) void fill_csr(
    const int* __restrict__ ei, int* __restrict__ cursor, int* __restrict__ esrc)
{
    const int e = blockIdx.x * blockDim.x + threadIdx.x;
    if (e >= N_EDGES) return;
    const int s = ei[e];
    const int d = ei[N_EDGES + e];
    const int p = atomicAdd(&cursor[d], 1);
    esrc[p] = s;
}

// ---------------------------------------------------------------------------
// K4: wave-per-node gather (unchanged; 41 us measured, ~6.2 TB/s logical).
// ---------------------------------------------------------------------------
__global__ __launch_bounds__(256) void gather_pass(
    const float* __restrict__ x, const int* __restrict__ offs,
    const int* __restrict__ esrc, float* __restrict__ agg)
{
    const int lane = threadIdx.x & 63;
    const int n    = (blockIdx.x * blockDim.x + threadIdx.x) >> 6;
    if (n >= N_NODES) return;

    const int beg = offs[n];
    const int end = offs[n + 1];

    float4 acc = make_float4(0.f, 0.f, 0.f, 0.f);
    for (int k0 = beg; k0 < end; k0 += 64) {
        const int cnt = min(64, end - k0);
        const int sv  = (lane < cnt) ? esrc[k0 + lane] : 0;
        int j = 0;
        for (; j + 4 <= cnt; j += 4) {
            const int s0 = __shfl(sv, j);
            const int s1 = __shfl(sv, j + 1);
            const int s2 = __shfl(sv, j + 2);
            const int s3 = __shfl(sv, j + 3);
            if (lane < 40) {
                const float4 v0 = ((const float4*)(x + (long)s0 * DIM))[lane];
                const float4 v1 = ((const float4*)(x + (long)s1 * DIM))[lane];
                const float4 v2 = ((const float4*)(x + (long)s2 * DIM))[lane];
                const float4 v3 = ((const float4*)(x + (long)s3 * DIM))[lane];
                acc.x += (v0.x + v1.x) + (v2.x + v3.x);
                acc.y += (v0.y + v1.y) + (v2.y + v3.y);
                acc.z += (v0.z + v1.z) + (v2.z + v3.z);
                acc.w += (v0.w + v1.w) + (v2.w + v3.w);
            }
        }
        for (; j < cnt; ++j) {
            const int s0 = __shfl(sv, j);
            if (lane < 40) {
                const float4 v0 = ((const float4*)(x + (long)s0 * DIM))[lane];
                acc.x += v0.x; acc.y += v0.y; acc.z += v0.z; acc.w += v0.w;
            }
        }
    }
    if (lane < 40)
        ((float4*)(agg + (long)n * DIM))[lane] = acc;
}

// ---------------------------------------------------------------------------
// K5: LDS-tiled node transform. Block owns 64 nodes. Rows + W0 + W1 staged in
// LDS once; both channels compute from LDS (operands never touch global in
// the inner loops — fixes round-6's latency-bound 78us).
//   Row pad +4 (ROWP=164): per-node b32/b128 reads land 2-way per bank (free).
//   scalar: thread=(node, chunk of 16 outputs), acc[16], LN via 4-lane shfl.
//   vector: thread=(node, 8 c-channels), o[24].
// In-place on agg. LDS = 41984 + 16384 + 4096 = 62464 B -> 2 blocks/CU.
// ---------------------------------------------------------------------------
#define ROWP 164
#define TNODES 64

__global__ __launch_bounds__(256) void node_tiled(
    float* __restrict__ agg,
    const float* __restrict__ W0, const float* __restrict__ W1,
    const float* __restrict__ ln_gamma, const float* __restrict__ ln_beta,
    const float* __restrict__ ew_accum)
{
    __shared__ float sA[TNODES * ROWP];   // 64 x 164 floats
    __shared__ float sW0[64 * 64];
    __shared__ float sW1[32 * 32];

    const int t = threadIdx.x;
    const int node0 = blockIdx.x * TNODES;

    // ---- stage weights (coalesced, L2-hot) ----
    {
        const float4* w04 = (const float4*)W0;   // 1024 float4
        float4* s04 = (float4*)sW0;
        #pragma unroll
        for (int i = 0; i < 4; ++i) s04[t + 256 * i] = w04[t + 256 * i];
        ((float4*)sW1)[t] = ((const float4*)W1)[t];   // 256 float4
    }
    // ---- stage 64 rows (coalesced float4, guarded) ----
    {
        #pragma unroll
        for (int i = 0; i < 10; ++i) {
            const int idx = t + 256 * i;         // 0..2559
            const int r   = idx / 40;
            const int c4  = idx - r * 40;
            const int n   = node0 + r;
            float4 v = make_float4(0.f, 0.f, 0.f, 0.f);
            if (n < N_NODES) v = ((const float4*)(agg + (long)n * DIM))[c4];
            *(float4*)(&sA[r * ROWP + 4 * c4]) = v;
        }
    }
    __syncthreads();

    const float ew   = ew_accum[0] * (1.0f / 400000.0f);
    const float s_m0 = ew * 0.125f;                 // / sqrt(64)
    const float s_m1 = ew * 0.17677669529663687f;   // / sqrt(32)

    const int nl   = t >> 2;          // 0..63 node within tile
    const int sub  = t & 3;           // chunk / c8
    const int node = node0 + nl;
    const bool valid = node < N_NODES;
    float* grow = agg + (long)(valid ? node : 0) * DIM;
    const float* aRow = sA + nl * ROWP;

    // ---------------- scalar channel ----------------
    float acc[16];
    #pragma unroll
    for (int j = 0; j < 16; ++j) acc[j] = 0.0f;

    #pragma unroll 8
    for (int k = 0; k < 64; ++k) {
        const float a = aRow[k];                        // ds b32, 2-way/bank
        const float4* w4 = (const float4*)(sW0 + k * 64 + sub * 16);
        #pragma unroll
        for (int p = 0; p < 4; ++p) {
            const float4 wv = w4[p];
            acc[4 * p]     = fmaf(a, wv.x, acc[4 * p]);
            acc[4 * p + 1] = fmaf(a, wv.y, acc[4 * p + 1]);
            acc[4 * p + 2] = fmaf(a, wv.z, acc[4 * p + 2]);
            acc[4 * p + 3] = fmaf(a, wv.w, acc[4 * p + 3]);
        }
    }

    float sum = 0.0f, sumsq = 0.0f;
    #pragma unroll
    for (int j = 0; j < 16; ++j) {
        acc[j] *= s_m0;
        sum += acc[j];
        sumsq = fmaf(acc[j], acc[j], sumsq);
    }
    sum += __shfl_xor(sum, 1);  sumsq += __shfl_xor(sumsq, 1);
    sum += __shfl_xor(sum, 2);  sumsq += __shfl_xor(sumsq, 2);
    const float mu   = sum * (1.0f / 64.0f);
    const float var  = sumsq * (1.0f / 64.0f) - mu * mu;
    const float rstd = rsqrtf(var + LN_EPS);

    if (valid) {
        const float4* g4 = (const float4*)(ln_gamma + sub * 16);
        const float4* b4 = (const float4*)(ln_beta  + sub * 16);
        float4* ro4 = (float4*)(grow + sub * 16);
        #pragma unroll
        for (int p = 0; p < 4; ++p) {
            const float4 g = g4[p];
            const float4 b = b4[p];
            const float t0 = (acc[4 * p]     - mu) * rstd * g.x + b.x;
            const float t1 = (acc[4 * p + 1] - mu) * rstd * g.y + b.y;
            const float t2 = (acc[4 * p + 2] - mu) * rstd * g.z + b.z;
            const float t3 = (acc[4 * p + 3] - mu) * rstd * g.w + b.w;
            float4 o;
            o.x = t0 / (1.0f + __expf(-t0));
            o.y = t1 / (1.0f + __expf(-t1));
            o.z = t2 / (1.0f + __expf(-t2));
            o.w = t3 / (1.0f + __expf(-t3));
            ro4[p] = o;
        }
    }

    // ---------------- vector channel ----------------
    float o[24];
    #pragma unroll
    for (int m = 0; m < 24; ++m) o[m] = 0.0f;

    const float* bRow = aRow + 64;
    #pragma unroll 2
    for (int tt = 0; tt < 8; ++tt) {            // cp = 4tt + r
        const float4 v0 = *(const float4*)(bRow + 12 * tt);
        const float4 v1 = *(const float4*)(bRow + 12 * tt + 4);
        const float4 v2 = *(const float4*)(bRow + 12 * tt + 8);
        const float a[12] = { v0.x, v0.y, v0.z, v0.w,
                              v1.x, v1.y, v1.z, v1.w,
                              v2.x, v2.y, v2.z, v2.w };
        #pragma unroll
        for (int r = 0; r < 4; ++r) {
            const int cp = 4 * tt + r;
            const float a0 = a[3 * r];
            const float a1 = a[3 * r + 1];
            const float a2 = a[3 * r + 2];
            const float4* w4 = (const float4*)(sW1 + cp * 32 + sub * 8);
            const float4 wA = w4[0];
            const float4 wB = w4[1];
            const float wc[8] = { wA.x, wA.y, wA.z, wA.w, wB.x, wB.y, wB.z, wB.w };
            #pragma unroll
            for (int cc = 0; cc < 8; ++cc) {
                o[3 * cc]     = fmaf(wc[cc], a0, o[3 * cc]);
                o[3 * cc + 1] = fmaf(wc[cc], a1, o[3 * cc + 1]);
                o[3 * cc + 2] = fmaf(wc[cc], a2, o[3 * cc + 2]);
            }
        }
    }

    if (valid) {
        float4* ro4 = (float4*)(grow + 64 + 24 * sub);
        #pragma unroll
        for (int q = 0; q < 6; ++q) {
            float4 ov;
            ov.x = o[4 * q]     * s_m1;
            ov.y = o[4 * q + 1] * s_m1;
            ov.z = o[4 * q + 2] * s_m1;
            ov.w = o[4 * q + 3] * s_m1;
            ro4[q] = ov;
        }
    }
}

extern "C" void kernel_launch(void* const* d_in, const int* in_sizes, int n_in,
                              void* d_out, int out_size, void* d_ws, size_t ws_size,
                              hipStream_t stream) {
    const float* x       = (const float*)d_in[0];
    const float* pos     = (const float*)d_in[1];
    const int*   ei      = (const int*)d_in[2];
    const float* W0      = (const float*)d_in[4];
    const float* W1      = (const float*)d_in[5];
    const float* centers = (const float*)d_in[6];
    const float* widths  = (const float*)d_in[7];
    const float* proj_w  = (const float*)d_in[8];
    const float* proj_b  = (const float*)d_in[9];
    const float* gamma   = (const float*)d_in[10];
    const float* beta    = (const float*)d_in[11];

    float* out  = (float*)d_out;
    int*   wsi  = (int*)d_ws;
    float* ew   = (float*)d_ws;
    int*   deg  = wsi + WS_DEG;
    int*   offs = wsi + WS_OFFS;
    int*   curs = wsi + WS_CURSOR;
    int*   esrc = wsi + WS_ESRC;

    hipMemsetAsync(d_ws, 0, (size_t)(WS_DEG + N_NODES) * sizeof(int), stream);

    const int eb = (N_EDGES + 255) / 256;
    hist_ew <<<eb, 256, 0, stream>>>(ei, pos, centers, widths, proj_w, proj_b, deg, ew);
    scan_deg<<<1, 1024, 0, stream>>>(deg, offs, curs);
    fill_csr<<<eb, 256, 0, stream>>>(ei, curs, esrc);

    const int nb = (N_NODES * 64 + 255) / 256;
    gather_pass<<<nb, 256, 0, stream>>>(x, offs, esrc, out);

    const int tiles = (N_NODES + TNODES - 1) / TNODES;   // 782
    node_tiled<<<tiles, 256, 0, stream>>>(out, W0, W1, gamma, beta, ew);
}